// Round 14
// baseline (97.752 us; speedup 1.0000x reference)
//
#include <hip/hip_runtime.h>

// GPT-2 MHA forward on MI355X (gfx950).
// B=4 T=1024 C=1024 H=16 DH=64. fp32 in/out, bf16 MFMA internally.
//
// Pipeline (4 dispatches):
//   cvt_fused:  x fp32 -> bf16 XB; {Wq(xQSCALE),Wk,Wv,Wp} -> transposed bf16
//   gemm_qkv128: 128^2 tile BK=64, grid 768 = 3 blocks/CU co-resident,
//               swizzled LDS (0 conflicts), coalesced normal-D epilogues.
//               Q,K -> QKVB rows; V -> VT[bh][d][t] directly.
//   attn:       causal flash attention, ONE q-tile per block, grid 1024 =
//               4 blocks/CU (4 waves/SIMD TLP), max-free exp2 softmax -> XB
//   gemm_proj:  BM=64 BN=128 BK=64, coalesced fp32 stores
//
// Workspace: 48 MB.

typedef unsigned short ushort_t;
typedef __attribute__((ext_vector_type(8))) __bf16 bf16x8;
typedef __attribute__((ext_vector_type(8))) unsigned short us8;
typedef __attribute__((ext_vector_type(4))) unsigned short us4;
typedef __attribute__((ext_vector_type(4))) float f32x4;

#define AS1 __attribute__((address_space(1)))
#define AS3 __attribute__((address_space(3)))

#define QSCALE 0.18033688011112042f   // 0.125 * log2(e)

__device__ __forceinline__ ushort_t f2bf(float f) {
  unsigned int u = __float_as_uint(f);
  u += 0x7fffu + ((u >> 16) & 1u);   // RTNE
  return (ushort_t)(u >> 16);
}

// native HW conversion (compiler packs pairs into v_cvt_pk_bf16_f32)
__device__ __forceinline__ ushort_t f2bf_hw(float f) {
  union { __bf16 b; ushort_t u; } cv;
  cv.b = (__bf16)f;
  return cv.u;
}

// ---------------- fused conversions ----------------
// blocks 0..4095: x fp32 -> bf16 (one float4/thread).
// blocks 4096..8191: one 32x32 transpose tile of {Wq,Wk,Wv,Wp} each.

__global__ void cvt_fused_kernel(const float* __restrict__ x,
                                 const float* __restrict__ Wq, const float* __restrict__ Wk,
                                 const float* __restrict__ Wv, const float* __restrict__ Wp,
                                 ushort_t* __restrict__ XB,
                                 ushort_t* __restrict__ WQKVT, ushort_t* __restrict__ WPT) {
  const int tid = threadIdx.x;
  if (blockIdx.x < 4096) {
    const int i = blockIdx.x * 256 + tid;
    const float4 v = reinterpret_cast<const float4*>(x)[i];
    us4 o;
    o.x = f2bf(v.x); o.y = f2bf(v.y); o.z = f2bf(v.z); o.w = f2bf(v.w);
    reinterpret_cast<us4*>(XB)[i] = o;
    return;
  }
  __shared__ float t[32][33];
  const int tt = blockIdx.x - 4096;     // 0..4095
  const int z = tt >> 10;               // matrix 0..3
  const int tile = tt & 1023;
  const int n0 = (tile & 31) * 32, k0 = (tile >> 5) * 32;
  const float* W = (z == 0) ? Wq : (z == 1) ? Wk : (z == 2) ? Wv : Wp;
  ushort_t* Wt = (z == 3) ? WPT : (WQKVT + ((size_t)z << 20));
  const float wscale = (z == 0) ? QSCALE : 1.0f;
  const int tx = tid & 31, ty = tid >> 5;   // 32 x 8
#pragma unroll
  for (int i = ty; i < 32; i += 8)
    t[i][tx] = W[(size_t)(k0 + i) * 1024 + n0 + tx];
  __syncthreads();
#pragma unroll
  for (int i = ty; i < 32; i += 8)
    Wt[(size_t)(n0 + i) * 1024 + k0 + tx] = f2bf(t[tx][i] * wscale);
}

// ---------------- QKV GEMM: 128x128, BK=64, grid 768 (3 blocks/CU) --------

__global__ __launch_bounds__(256, 3) void gemm_qkv128_kernel(
    const ushort_t* __restrict__ A, const ushort_t* __restrict__ Bt,
    const float* __restrict__ bq, const float* __restrict__ bk,
    const float* __restrict__ bv, ushort_t* __restrict__ QKVB,
    ushort_t* __restrict__ VT) {
  __shared__ ushort_t As[128 * 64];   // 16KB
  __shared__ ushort_t Bs[128 * 64];   // 16KB
  const int tid = threadIdx.x;
  const int wave = tid >> 6, lane = tid & 63;
  const int lgrp = lane >> 4, lmod = lane & 15;
  const int wr = wave >> 1, wc = wave & 1;
  // bijective XCD swizzle: 768 blocks, 96 per XCD
  const int swz = (blockIdx.x & 7) * 96 + (blockIdx.x >> 3);
  const int rowt = swz / 24, colt = swz % 24;
  const int row0 = rowt * 128, col0 = colt * 128;
  const bool isV = (colt >= 16);

  const int sslot = (tid & 7) ^ ((tid >> 3) & 7);
  const int srow = tid >> 3;          // 0..31, +32 per i

  auto stage = [&](int t) {
    const ushort_t* Asrc = A + (size_t)row0 * 1024 + t * 64 + sslot * 8;
    const ushort_t* Bsrc = Bt + (size_t)col0 * 1024 + t * 64 + sslot * 8;
#pragma unroll
    for (int i = 0; i < 4; ++i) {
      __builtin_amdgcn_global_load_lds(
          (AS1 void*)(Asrc + (size_t)(i * 32 + srow) * 1024),
          (AS3 void*)(As + (i * 256 + wave * 64) * 8), 16, 0, 0);
      __builtin_amdgcn_global_load_lds(
          (AS1 void*)(Bsrc + (size_t)(i * 32 + srow) * 1024),
          (AS3 void*)(Bs + (i * 256 + wave * 64) * 8), 16, 0, 0);
    }
  };

  f32x4 acc[4][4] = {};
  const int xm = lmod & 7;

  for (int t = 0; t < 16; ++t) {
    stage(t);
    asm volatile("s_waitcnt vmcnt(0)" ::: "memory");
    __builtin_amdgcn_s_barrier();     // tile visible

    bf16x8 af[4][2], bfr[4][2];
#pragma unroll
    for (int mi = 0; mi < 4; ++mi)
#pragma unroll
      for (int ks = 0; ks < 2; ++ks)
        af[mi][ks] = *reinterpret_cast<const bf16x8*>(
            &As[(wr * 64 + mi * 16 + lmod) * 64 + (((ks << 2) | lgrp) ^ xm) * 8]);
#pragma unroll
    for (int ni = 0; ni < 4; ++ni)
#pragma unroll
      for (int ks = 0; ks < 2; ++ks)
        bfr[ni][ks] = *reinterpret_cast<const bf16x8*>(
            &Bs[(wc * 64 + ni * 16 + lmod) * 64 + (((ks << 2) | lgrp) ^ xm) * 8]);

    __builtin_amdgcn_s_setprio(1);
#pragma unroll
    for (int mi = 0; mi < 4; ++mi)
#pragma unroll
      for (int ni = 0; ni < 4; ++ni)
#pragma unroll
        for (int ks = 0; ks < 2; ++ks)
          acc[mi][ni] = __builtin_amdgcn_mfma_f32_16x16x32_bf16(
              af[mi][ks], bfr[ni][ks], acc[mi][ni], 0, 0, 0);
    __builtin_amdgcn_s_setprio(0);
    __builtin_amdgcn_s_barrier();     // readers done; next stage may overwrite
  }

  if (!isV) {
    // normal D: coalesced (consecutive lanes -> consecutive cols)
    const float* bsel = (col0 < 1024) ? bq : bk;
    const float bsc = (col0 < 1024) ? QSCALE : 1.0f;
    float bvv[4];
#pragma unroll
    for (int ni = 0; ni < 4; ++ni)
      bvv[ni] = bsel[(col0 & 1023) + wc * 64 + ni * 16 + lmod] * bsc;
#pragma unroll
    for (int mi = 0; mi < 4; ++mi) {
#pragma unroll
      for (int ni = 0; ni < 4; ++ni) {
        const int col = col0 + wc * 64 + ni * 16 + lmod;
#pragma unroll
        for (int r = 0; r < 4; ++r) {
          const int row = row0 + wr * 64 + mi * 16 + lgrp * 4 + r;
          QKVB[(size_t)row * 3072 + col] = f2bf(acc[mi][ni][r] + bvv[ni]);
        }
      }
    }
  } else {
    // V: lane -> col hd, 4 consecutive tokens per quad -> VT[bh][d][t]
    float bvv[4];
#pragma unroll
    for (int ni = 0; ni < 4; ++ni)
      bvv[ni] = bv[(col0 - 2048) + wc * 64 + ni * 16 + lmod];
#pragma unroll
    for (int mi = 0; mi < 4; ++mi) {
#pragma unroll
      for (int ni = 0; ni < 4; ++ni) {
        const int hd = (col0 - 2048) + wc * 64 + ni * 16 + lmod;
        const int R = row0 + wr * 64 + mi * 16 + lgrp * 4;
        const int bb = R >> 10, tl = R & 1023;
        us4 o;
#pragma unroll
        for (int r = 0; r < 4; ++r) o[r] = f2bf(acc[mi][ni][r] + bvv[ni]);
        *reinterpret_cast<us4*>(VT + ((size_t)(bb * 16 + (hd >> 6)) * 64 + (hd & 63)) * 1024 + tl) = o;
      }
    }
  }
}

// ---------------- out-proj GEMM: BM=64, BN=128, BK=64 ----------------

__global__ __launch_bounds__(256, 2) void gemm_proj_kernel(
    const ushort_t* __restrict__ A, const ushort_t* __restrict__ Bt,
    const float* __restrict__ bias, float* __restrict__ Cout) {
  __shared__ ushort_t As[64 * 64];    // 8KB
  __shared__ ushort_t Bs[128 * 64];   // 16KB
  const int tid = threadIdx.x;
  const int wave = tid >> 6, lane = tid & 63;
  const int lgrp = lane >> 4, lmod = lane & 15;
  const int wr = wave >> 1, wc = wave & 1;
  const int swz = (blockIdx.x & 7) * 64 + (blockIdx.x >> 3);  // 512 blocks
  const int row0 = (swz >> 3) * 64, col0 = (swz & 7) * 128;

  const int sslot = (tid & 7) ^ ((tid >> 3) & 7);
  const int srow = tid >> 3;

  auto stage = [&](int t) {
    const ushort_t* Asrc = A + (size_t)row0 * 1024 + t * 64 + sslot * 8;
    const ushort_t* Bsrc = Bt + (size_t)col0 * 1024 + t * 64 + sslot * 8;
#pragma unroll
    for (int i = 0; i < 2; ++i)       // A: 512 chunks
      __builtin_amdgcn_global_load_lds(
          (AS1 void*)(Asrc + (size_t)(i * 32 + srow) * 1024),
          (AS3 void*)(As + (i * 256 + wave * 64) * 8), 16, 0, 0);
#pragma unroll
    for (int i = 0; i < 4; ++i)       // B: 1024 chunks
      __builtin_amdgcn_global_load_lds(
          (AS1 void*)(Bsrc + (size_t)(i * 32 + srow) * 1024),
          (AS3 void*)(Bs + (i * 256 + wave * 64) * 8), 16, 0, 0);
  };

  f32x4 acc[2][4] = {};
  const int xm = lmod & 7;

  for (int t = 0; t < 16; ++t) {
    stage(t);
    asm volatile("s_waitcnt vmcnt(0)" ::: "memory");
    __builtin_amdgcn_s_barrier();

    bf16x8 af[2][2], bfr[4][2];
#pragma unroll
    for (int mi = 0; mi < 2; ++mi)
#pragma unroll
      for (int ks = 0; ks < 2; ++ks)
        af[mi][ks] = *reinterpret_cast<const bf16x8*>(
            &As[(wr * 32 + mi * 16 + lmod) * 64 + (((ks << 2) | lgrp) ^ xm) * 8]);
#pragma unroll
    for (int ni = 0; ni < 4; ++ni)
#pragma unroll
      for (int ks = 0; ks < 2; ++ks)
        bfr[ni][ks] = *reinterpret_cast<const bf16x8*>(
            &Bs[(wc * 64 + ni * 16 + lmod) * 64 + (((ks << 2) | lgrp) ^ xm) * 8]);

    __builtin_amdgcn_s_setprio(1);
#pragma unroll
    for (int mi = 0; mi < 2; ++mi)
#pragma unroll
      for (int ni = 0; ni < 4; ++ni)
#pragma unroll
        for (int ks = 0; ks < 2; ++ks)
          acc[mi][ni] = __builtin_amdgcn_mfma_f32_16x16x32_bf16(
              af[mi][ks], bfr[ni][ks], acc[mi][ni], 0, 0, 0);
    __builtin_amdgcn_s_setprio(0);
    __builtin_amdgcn_s_barrier();
  }

  float bvv[4];
#pragma unroll
  for (int ni = 0; ni < 4; ++ni) bvv[ni] = bias[col0 + wc * 64 + ni * 16 + lmod];
#pragma unroll
  for (int mi = 0; mi < 2; ++mi)
#pragma unroll
    for (int ni = 0; ni < 4; ++ni) {
      const int col = col0 + wc * 64 + ni * 16 + lmod;
#pragma unroll
      for (int r = 0; r < 4; ++r) {
        const int row = row0 + wr * 32 + mi * 16 + lgrp * 4 + r;
        Cout[(size_t)row * 1024 + col] = acc[mi][ni][r] + bvv[ni];
      }
    }
}

// ---------------- causal flash attention, one q-tile per block ------------
// grid 1024 = 16 q-tiles x 64 bh -> 4 blocks/CU resident (4 waves/SIMD TLP).
// pslot->p alternates heavy/light (0,15,1,14,...) so adjacent blocks sum to
// ~constant work; dynamic refill over 1024 blocks amortizes the rest.
// Max-free exp2 softmax (scores bounded; log2e folded into Wq), deferred
// l-reduce. LDS 27.6KB/block.

__global__ __launch_bounds__(256, 4) void attn_kernel(
    const ushort_t* __restrict__ QKV, const ushort_t* __restrict__ VT,
    ushort_t* __restrict__ Og) {
  const int bid = blockIdx.x;
  const int swz = (bid & 7) * 128 + (bid >> 3);   // XCD-chunked, 1024 blocks
  const int pslot = swz & 15, bh = swz >> 4;
  const int p = (pslot & 1) ? (15 - (pslot >> 1)) : (pslot >> 1);
  const int b = bh >> 4, h = bh & 15;
  const int tid = threadIdx.x;
  const int wave = tid >> 6, lane = tid & 63;
  const int lgrp = lane >> 4, lmod = lane & 15;

  __shared__ ushort_t Ks[64 * 72];     // K tile [kc][dh], +8 pad
  __shared__ ushort_t Vs[64 * 72];     // V^T tile [dh][kc], +8 pad
  __shared__ ushort_t Ps[4][16 * 72];  // per-wave P

  const size_t xrow0 = (size_t)b * 1024;
  const int qr0 = p * 64 + wave * 16;

  bf16x8 qf[2];
#pragma unroll
  for (int ks = 0; ks < 2; ++ks)
    qf[ks] = *reinterpret_cast<const bf16x8*>(
        QKV + (xrow0 + qr0 + lmod) * 3072 + h * 64 + ks * 32 + lgrp * 8);

  f32x4 oacc[4] = {};
  float lsum[4] = {0.f, 0.f, 0.f, 0.f};

  const int sr = tid >> 3;
  const int scc = (tid & 7) << 3;
  us8 kreg0, kreg1, vreg0, vreg1;

  auto load_tile = [&](int j) {
    const ushort_t* kp = QKV + (xrow0 + j * 64 + sr) * 3072 + 1024 + h * 64 + scc;
    kreg0 = *reinterpret_cast<const us8*>(kp);
    kreg1 = *reinterpret_cast<const us8*>(kp + 32 * 3072);
    const ushort_t* vp = VT + ((size_t)bh * 64 + sr) * 1024 + j * 64 + scc;
    vreg0 = *reinterpret_cast<const us8*>(vp);
    vreg1 = *reinterpret_cast<const us8*>(vp + 32 * 1024);
  };
  auto write_tile = [&]() {
    *reinterpret_cast<us8*>(&Ks[sr * 72 + scc]) = kreg0;
    *reinterpret_cast<us8*>(&Ks[(32 + sr) * 72 + scc]) = kreg1;
    *reinterpret_cast<us8*>(&Vs[sr * 72 + scc]) = vreg0;
    *reinterpret_cast<us8*>(&Vs[(32 + sr) * 72 + scc]) = vreg1;
  };

  for (int j = 0; j <= p; ++j) {
    if (j == 0) load_tile(0);
    __syncthreads();
    write_tile();
    __syncthreads();
    if (j < p) load_tile(j + 1);

    f32x4 s[4];
    __builtin_amdgcn_s_setprio(1);
#pragma unroll
    for (int cg = 0; cg < 4; ++cg) {
      f32x4 a = {};
#pragma unroll
      for (int ks = 0; ks < 2; ++ks) {
        bf16x8 kf = *reinterpret_cast<const bf16x8*>(
            &Ks[(cg * 16 + lmod) * 72 + ks * 32 + lgrp * 8]);
        a = __builtin_amdgcn_mfma_f32_16x16x32_bf16(qf[ks], kf, a, 0, 0, 0);
      }
      s[cg] = a;
    }
    __builtin_amdgcn_s_setprio(0);

    if (j == p) {   // diagonal tile: mask k > q
      const int qloc = wave * 16 + lgrp * 4;
#pragma unroll
      for (int cg = 0; cg < 4; ++cg) {
        const int kcol = cg * 16 + lmod;
#pragma unroll
        for (int r = 0; r < 4; ++r)
          if (kcol > qloc + r) s[cg][r] = -1e30f;
      }
    }

#pragma unroll
    for (int cg = 0; cg < 4; ++cg)
#pragma unroll
      for (int r = 0; r < 4; ++r) s[cg][r] = exp2f(s[cg][r]);
#pragma unroll
    for (int r = 0; r < 4; ++r)
      lsum[r] += (s[0][r] + s[1][r]) + (s[2][r] + s[3][r]);
#pragma unroll
    for (int cg = 0; cg < 4; ++cg)
#pragma unroll
      for (int r = 0; r < 4; ++r)
        Ps[wave][(lgrp * 4 + r) * 72 + cg * 16 + lmod] = f2bf_hw(s[cg][r]);

    __builtin_amdgcn_s_setprio(1);
#pragma unroll
    for (int ks = 0; ks < 2; ++ks) {
      bf16x8 pf = *reinterpret_cast<const bf16x8*>(
          &Ps[wave][lmod * 72 + ks * 32 + lgrp * 8]);
#pragma unroll
      for (int dhg = 0; dhg < 4; ++dhg) {
        bf16x8 vf = *reinterpret_cast<const bf16x8*>(
            &Vs[(dhg * 16 + lmod) * 72 + ks * 32 + lgrp * 8]);
        oacc[dhg] = __builtin_amdgcn_mfma_f32_16x16x32_bf16(pf, vf, oacc[dhg], 0, 0, 0);
      }
    }
    __builtin_amdgcn_s_setprio(0);
  }

  // deferred l reduction across the 16-lane row groups
#pragma unroll
  for (int m = 1; m <= 8; m <<= 1)
#pragma unroll
    for (int r = 0; r < 4; ++r) lsum[r] += __shfl_xor(lsum[r], m);

#pragma unroll
  for (int dhg = 0; dhg < 4; ++dhg) {
    const int col = h * 64 + dhg * 16 + lmod;
#pragma unroll
    for (int r = 0; r < 4; ++r)
      Og[(xrow0 + qr0 + lgrp * 4 + r) * 1024 + col] = f2bf_hw(oacc[dhg][r] / lsum[r]);
  }
}

// ---------------- launch ----------------

extern "C" void kernel_launch(void* const* d_in, const int* in_sizes, int n_in,
                              void* d_out, int out_size, void* d_ws, size_t ws_size,
                              hipStream_t stream) {
  const float* x  = (const float*)d_in[0];
  const float* Wq = (const float*)d_in[1];
  const float* bq = (const float*)d_in[2];
  const float* Wk = (const float*)d_in[3];
  const float* bk = (const float*)d_in[4];
  const float* Wv = (const float*)d_in[5];
  const float* bv = (const float*)d_in[6];
  const float* Wp = (const float*)d_in[7];
  const float* bp = (const float*)d_in[8];
  float* out = (float*)d_out;

  char* ws = (char*)d_ws;
  ushort_t* XB    = (ushort_t*)(ws);                  // 8MB; reused as ctx
  ushort_t* WQKVT = (ushort_t*)(ws + ( 8ull << 20));  // 6MB [3072][1024]
  ushort_t* WPT   = (ushort_t*)(ws + (14ull << 20));  // 2MB [1024][1024]
  ushort_t* QKVB  = (ushort_t*)(ws + (16ull << 20));  // 24MB [4096][3072] (V region unused)
  ushort_t* VT    = (ushort_t*)(ws + (40ull << 20));  // 8MB [64bh][64d][1024t]

  cvt_fused_kernel<<<8192, 256, 0, stream>>>(x, Wq, Wk, Wv, Wp, XB, WQKVT, WPT);
  gemm_qkv128_kernel<<<768, 256, 0, stream>>>(XB, WQKVT, bq, bk, bv, QKVB, VT);
  attn_kernel<<<1024, 256, 0, stream>>>(QKVB, VT, XB);
  gemm_proj_kernel<<<512, 256, 0, stream>>>(XB, WPT, bp, out);
}

// Round 15
// 86.230 us; speedup vs baseline: 1.1336x; 1.1336x over previous
//
#include <hip/hip_runtime.h>

// GPT-2 MHA forward on MI355X (gfx950).
// B=4 T=1024 C=1024 H=16 DH=64. fp32 in/out, bf16 MFMA internally.
//
// Pipeline (4 dispatches):
//   cvt_fused:  x fp32 -> bf16 XB; {Wq(xQSCALE),Wk,Wv,Wp} -> transposed bf16
//   gemm_qkv128: 128^2 tile BK=64, grid 768 = 3 blocks/CU co-resident,
//               swizzled LDS (0 conflicts), coalesced normal-D epilogues.
//               Q,K -> QKVB rows; V -> VT[bh][d][t] directly.
//   attn:       causal flash attention, paired q-tiles, max-free exp2 softmax,
//               dual-step K/V fragment sharing -> XB
//   gemm_proj:  BM=64 BN=128 BK=64, coalesced fp32 stores
//
// Workspace: 48 MB.

typedef unsigned short ushort_t;
typedef __attribute__((ext_vector_type(8))) __bf16 bf16x8;
typedef __attribute__((ext_vector_type(8))) unsigned short us8;
typedef __attribute__((ext_vector_type(4))) unsigned short us4;
typedef __attribute__((ext_vector_type(4))) float f32x4;

#define AS1 __attribute__((address_space(1)))
#define AS3 __attribute__((address_space(3)))

#define QSCALE 0.18033688011112042f   // 0.125 * log2(e)

__device__ __forceinline__ ushort_t f2bf(float f) {
  unsigned int u = __float_as_uint(f);
  u += 0x7fffu + ((u >> 16) & 1u);   // RTNE
  return (ushort_t)(u >> 16);
}

// native HW conversion (compiler packs pairs into v_cvt_pk_bf16_f32)
__device__ __forceinline__ ushort_t f2bf_hw(float f) {
  union { __bf16 b; ushort_t u; } cv;
  cv.b = (__bf16)f;
  return cv.u;
}

// ---------------- fused conversions ----------------
// blocks 0..4095: x fp32 -> bf16 (one float4/thread).
// blocks 4096..8191: one 32x32 transpose tile of {Wq,Wk,Wv,Wp} each.

__global__ void cvt_fused_kernel(const float* __restrict__ x,
                                 const float* __restrict__ Wq, const float* __restrict__ Wk,
                                 const float* __restrict__ Wv, const float* __restrict__ Wp,
                                 ushort_t* __restrict__ XB,
                                 ushort_t* __restrict__ WQKVT, ushort_t* __restrict__ WPT) {
  const int tid = threadIdx.x;
  if (blockIdx.x < 4096) {
    const int i = blockIdx.x * 256 + tid;
    const float4 v = reinterpret_cast<const float4*>(x)[i];
    us4 o;
    o.x = f2bf(v.x); o.y = f2bf(v.y); o.z = f2bf(v.z); o.w = f2bf(v.w);
    reinterpret_cast<us4*>(XB)[i] = o;
    return;
  }
  __shared__ float t[32][33];
  const int tt = blockIdx.x - 4096;     // 0..4095
  const int z = tt >> 10;               // matrix 0..3
  const int tile = tt & 1023;
  const int n0 = (tile & 31) * 32, k0 = (tile >> 5) * 32;
  const float* W = (z == 0) ? Wq : (z == 1) ? Wk : (z == 2) ? Wv : Wp;
  ushort_t* Wt = (z == 3) ? WPT : (WQKVT + ((size_t)z << 20));
  const float wscale = (z == 0) ? QSCALE : 1.0f;
  const int tx = tid & 31, ty = tid >> 5;   // 32 x 8
#pragma unroll
  for (int i = ty; i < 32; i += 8)
    t[i][tx] = W[(size_t)(k0 + i) * 1024 + n0 + tx];
  __syncthreads();
#pragma unroll
  for (int i = ty; i < 32; i += 8)
    Wt[(size_t)(n0 + i) * 1024 + k0 + tx] = f2bf(t[tx][i] * wscale);
}

// ---------------- QKV GEMM: 128x128, BK=64, grid 768 (3 blocks/CU) --------

__global__ __launch_bounds__(256, 3) void gemm_qkv128_kernel(
    const ushort_t* __restrict__ A, const ushort_t* __restrict__ Bt,
    const float* __restrict__ bq, const float* __restrict__ bk,
    const float* __restrict__ bv, ushort_t* __restrict__ QKVB,
    ushort_t* __restrict__ VT) {
  __shared__ ushort_t As[128 * 64];   // 16KB
  __shared__ ushort_t Bs[128 * 64];   // 16KB
  const int tid = threadIdx.x;
  const int wave = tid >> 6, lane = tid & 63;
  const int lgrp = lane >> 4, lmod = lane & 15;
  const int wr = wave >> 1, wc = wave & 1;
  // bijective XCD swizzle: 768 blocks, 96 per XCD
  const int swz = (blockIdx.x & 7) * 96 + (blockIdx.x >> 3);
  const int rowt = swz / 24, colt = swz % 24;
  const int row0 = rowt * 128, col0 = colt * 128;
  const bool isV = (colt >= 16);

  const int sslot = (tid & 7) ^ ((tid >> 3) & 7);
  const int srow = tid >> 3;          // 0..31, +32 per i

  auto stage = [&](int t) {
    const ushort_t* Asrc = A + (size_t)row0 * 1024 + t * 64 + sslot * 8;
    const ushort_t* Bsrc = Bt + (size_t)col0 * 1024 + t * 64 + sslot * 8;
#pragma unroll
    for (int i = 0; i < 4; ++i) {
      __builtin_amdgcn_global_load_lds(
          (AS1 void*)(Asrc + (size_t)(i * 32 + srow) * 1024),
          (AS3 void*)(As + (i * 256 + wave * 64) * 8), 16, 0, 0);
      __builtin_amdgcn_global_load_lds(
          (AS1 void*)(Bsrc + (size_t)(i * 32 + srow) * 1024),
          (AS3 void*)(Bs + (i * 256 + wave * 64) * 8), 16, 0, 0);
    }
  };

  f32x4 acc[4][4] = {};
  const int xm = lmod & 7;

  for (int t = 0; t < 16; ++t) {
    stage(t);
    asm volatile("s_waitcnt vmcnt(0)" ::: "memory");
    __builtin_amdgcn_s_barrier();     // tile visible

    bf16x8 af[4][2], bfr[4][2];
#pragma unroll
    for (int mi = 0; mi < 4; ++mi)
#pragma unroll
      for (int ks = 0; ks < 2; ++ks)
        af[mi][ks] = *reinterpret_cast<const bf16x8*>(
            &As[(wr * 64 + mi * 16 + lmod) * 64 + (((ks << 2) | lgrp) ^ xm) * 8]);
#pragma unroll
    for (int ni = 0; ni < 4; ++ni)
#pragma unroll
      for (int ks = 0; ks < 2; ++ks)
        bfr[ni][ks] = *reinterpret_cast<const bf16x8*>(
            &Bs[(wc * 64 + ni * 16 + lmod) * 64 + (((ks << 2) | lgrp) ^ xm) * 8]);

    __builtin_amdgcn_s_setprio(1);
#pragma unroll
    for (int mi = 0; mi < 4; ++mi)
#pragma unroll
      for (int ni = 0; ni < 4; ++ni)
#pragma unroll
        for (int ks = 0; ks < 2; ++ks)
          acc[mi][ni] = __builtin_amdgcn_mfma_f32_16x16x32_bf16(
              af[mi][ks], bfr[ni][ks], acc[mi][ni], 0, 0, 0);
    __builtin_amdgcn_s_setprio(0);
    __builtin_amdgcn_s_barrier();     // readers done; next stage may overwrite
  }

  if (!isV) {
    // normal D: coalesced (consecutive lanes -> consecutive cols)
    const float* bsel = (col0 < 1024) ? bq : bk;
    const float bsc = (col0 < 1024) ? QSCALE : 1.0f;
    float bvv[4];
#pragma unroll
    for (int ni = 0; ni < 4; ++ni)
      bvv[ni] = bsel[(col0 & 1023) + wc * 64 + ni * 16 + lmod] * bsc;
#pragma unroll
    for (int mi = 0; mi < 4; ++mi) {
#pragma unroll
      for (int ni = 0; ni < 4; ++ni) {
        const int col = col0 + wc * 64 + ni * 16 + lmod;
#pragma unroll
        for (int r = 0; r < 4; ++r) {
          const int row = row0 + wr * 64 + mi * 16 + lgrp * 4 + r;
          QKVB[(size_t)row * 3072 + col] = f2bf(acc[mi][ni][r] + bvv[ni]);
        }
      }
    }
  } else {
    // V: lane -> col hd, 4 consecutive tokens per quad -> VT[bh][d][t]
    float bvv[4];
#pragma unroll
    for (int ni = 0; ni < 4; ++ni)
      bvv[ni] = bv[(col0 - 2048) + wc * 64 + ni * 16 + lmod];
#pragma unroll
    for (int mi = 0; mi < 4; ++mi) {
#pragma unroll
      for (int ni = 0; ni < 4; ++ni) {
        const int hd = (col0 - 2048) + wc * 64 + ni * 16 + lmod;
        const int R = row0 + wr * 64 + mi * 16 + lgrp * 4;
        const int bb = R >> 10, tl = R & 1023;
        us4 o;
#pragma unroll
        for (int r = 0; r < 4; ++r) o[r] = f2bf(acc[mi][ni][r] + bvv[ni]);
        *reinterpret_cast<us4*>(VT + ((size_t)(bb * 16 + (hd >> 6)) * 64 + (hd & 63)) * 1024 + tl) = o;
      }
    }
  }
}

// ---------------- out-proj GEMM: BM=64, BN=128, BK=64 ----------------

__global__ __launch_bounds__(256, 2) void gemm_proj_kernel(
    const ushort_t* __restrict__ A, const ushort_t* __restrict__ Bt,
    const float* __restrict__ bias, float* __restrict__ Cout) {
  __shared__ ushort_t As[64 * 64];    // 8KB
  __shared__ ushort_t Bs[128 * 64];   // 16KB
  const int tid = threadIdx.x;
  const int wave = tid >> 6, lane = tid & 63;
  const int lgrp = lane >> 4, lmod = lane & 15;
  const int wr = wave >> 1, wc = wave & 1;
  const int swz = (blockIdx.x & 7) * 64 + (blockIdx.x >> 3);  // 512 blocks
  const int row0 = (swz >> 3) * 64, col0 = (swz & 7) * 128;

  const int sslot = (tid & 7) ^ ((tid >> 3) & 7);
  const int srow = tid >> 3;

  auto stage = [&](int t) {
    const ushort_t* Asrc = A + (size_t)row0 * 1024 + t * 64 + sslot * 8;
    const ushort_t* Bsrc = Bt + (size_t)col0 * 1024 + t * 64 + sslot * 8;
#pragma unroll
    for (int i = 0; i < 2; ++i)       // A: 512 chunks
      __builtin_amdgcn_global_load_lds(
          (AS1 void*)(Asrc + (size_t)(i * 32 + srow) * 1024),
          (AS3 void*)(As + (i * 256 + wave * 64) * 8), 16, 0, 0);
#pragma unroll
    for (int i = 0; i < 4; ++i)       // B: 1024 chunks
      __builtin_amdgcn_global_load_lds(
          (AS1 void*)(Bsrc + (size_t)(i * 32 + srow) * 1024),
          (AS3 void*)(Bs + (i * 256 + wave * 64) * 8), 16, 0, 0);
  };

  f32x4 acc[2][4] = {};
  const int xm = lmod & 7;

  for (int t = 0; t < 16; ++t) {
    stage(t);
    asm volatile("s_waitcnt vmcnt(0)" ::: "memory");
    __builtin_amdgcn_s_barrier();

    bf16x8 af[2][2], bfr[4][2];
#pragma unroll
    for (int mi = 0; mi < 2; ++mi)
#pragma unroll
      for (int ks = 0; ks < 2; ++ks)
        af[mi][ks] = *reinterpret_cast<const bf16x8*>(
            &As[(wr * 32 + mi * 16 + lmod) * 64 + (((ks << 2) | lgrp) ^ xm) * 8]);
#pragma unroll
    for (int ni = 0; ni < 4; ++ni)
#pragma unroll
      for (int ks = 0; ks < 2; ++ks)
        bfr[ni][ks] = *reinterpret_cast<const bf16x8*>(
            &Bs[(wc * 64 + ni * 16 + lmod) * 64 + (((ks << 2) | lgrp) ^ xm) * 8]);

    __builtin_amdgcn_s_setprio(1);
#pragma unroll
    for (int mi = 0; mi < 2; ++mi)
#pragma unroll
      for (int ni = 0; ni < 4; ++ni)
#pragma unroll
        for (int ks = 0; ks < 2; ++ks)
          acc[mi][ni] = __builtin_amdgcn_mfma_f32_16x16x32_bf16(
              af[mi][ks], bfr[ni][ks], acc[mi][ni], 0, 0, 0);
    __builtin_amdgcn_s_setprio(0);
    __builtin_amdgcn_s_barrier();
  }

  float bvv[4];
#pragma unroll
  for (int ni = 0; ni < 4; ++ni) bvv[ni] = bias[col0 + wc * 64 + ni * 16 + lmod];
#pragma unroll
  for (int mi = 0; mi < 2; ++mi)
#pragma unroll
    for (int ni = 0; ni < 4; ++ni) {
      const int col = col0 + wc * 64 + ni * 16 + lmod;
#pragma unroll
      for (int r = 0; r < 4; ++r) {
        const int row = row0 + wr * 32 + mi * 16 + lgrp * 4 + r;
        Cout[(size_t)row * 1024 + col] = acc[mi][ni][r] + bvv[ni];
      }
    }
}

// ---------------- causal flash attention, paired q-tiles ----------------
// grid 512 = 8 pairs x 64 bh; q-tiles p and 15-p per block, 17 steps each.
// Max-free exp2 softmax (scores bounded; log2e folded into Wq), deferred
// l-reduce. On iterations j<=p both q-tiles are active: step_dual shares
// every K/V fragment read between them (2 MFMAs per ds_read).

__global__ __launch_bounds__(256, 2) void attn_kernel(
    const ushort_t* __restrict__ QKV, const ushort_t* __restrict__ VT,
    ushort_t* __restrict__ Og) {
  const int bid = blockIdx.x;
  const int swz = (bid & 7) * 64 + (bid >> 3);   // XCD-chunked
  const int p = swz & 7, bh = swz >> 3;
  const int b = bh >> 4, h = bh & 15;
  const int jmax = 15 - p;
  const int tid = threadIdx.x;
  const int wave = tid >> 6, lane = tid & 63;
  const int lgrp = lane >> 4, lmod = lane & 15;

  __shared__ ushort_t Ks[64 * 72];        // K tile [kc][dh], +8 pad
  __shared__ ushort_t Vs[64 * 72];        // V^T tile [dh][kc], +8 pad
  __shared__ ushort_t Ps[4][2][16 * 72];  // per-wave P, [lo/hi]

  const size_t xrow0 = (size_t)b * 1024;
  const int qlo = p * 64 + wave * 16;
  const int qhi = jmax * 64 + wave * 16;

  bf16x8 qfl[2], qfh[2];
#pragma unroll
  for (int ks = 0; ks < 2; ++ks) {
    qfl[ks] = *reinterpret_cast<const bf16x8*>(
        QKV + (xrow0 + qlo + lmod) * 3072 + h * 64 + ks * 32 + lgrp * 8);
    qfh[ks] = *reinterpret_cast<const bf16x8*>(
        QKV + (xrow0 + qhi + lmod) * 3072 + h * 64 + ks * 32 + lgrp * 8);
  }

  f32x4 ol[4] = {}, oh[4] = {};
  float ll[4] = {0.f, 0.f, 0.f, 0.f}, lh[4] = {0.f, 0.f, 0.f, 0.f};

  const int sr = tid >> 3;
  const int scc = (tid & 7) << 3;
  us8 kreg0, kreg1, vreg0, vreg1;

  auto load_tile = [&](int j) {
    const ushort_t* kp = QKV + (xrow0 + j * 64 + sr) * 3072 + 1024 + h * 64 + scc;
    kreg0 = *reinterpret_cast<const us8*>(kp);
    kreg1 = *reinterpret_cast<const us8*>(kp + 32 * 3072);
    const ushort_t* vp = VT + ((size_t)bh * 64 + sr) * 1024 + j * 64 + scc;
    vreg0 = *reinterpret_cast<const us8*>(vp);
    vreg1 = *reinterpret_cast<const us8*>(vp + 32 * 1024);
  };
  auto write_tile = [&]() {
    *reinterpret_cast<us8*>(&Ks[sr * 72 + scc]) = kreg0;
    *reinterpret_cast<us8*>(&Ks[(32 + sr) * 72 + scc]) = kreg1;
    *reinterpret_cast<us8*>(&Vs[sr * 72 + scc]) = vreg0;
    *reinterpret_cast<us8*>(&Vs[(32 + sr) * 72 + scc]) = vreg1;
  };

  // masking helper (diag tile: kcol > qrow -> -inf)
  auto mask_diag = [&](f32x4* s) {
    const int qloc = wave * 16 + lgrp * 4;
#pragma unroll
    for (int cg = 0; cg < 4; ++cg) {
      const int kcol = cg * 16 + lmod;
#pragma unroll
      for (int r = 0; r < 4; ++r)
        if (kcol > qloc + r) s[cg][r] = -1e30f;
    }
  };

  // single-tile step (hi tile on iterations j > p)
  auto step = [&](const bf16x8* qf, f32x4* oacc, float* lsum, bool diag) {
    f32x4 s[4];
    __builtin_amdgcn_s_setprio(1);
#pragma unroll
    for (int cg = 0; cg < 4; ++cg) {
      f32x4 a = {};
#pragma unroll
      for (int ks = 0; ks < 2; ++ks) {
        bf16x8 kf = *reinterpret_cast<const bf16x8*>(
            &Ks[(cg * 16 + lmod) * 72 + ks * 32 + lgrp * 8]);
        a = __builtin_amdgcn_mfma_f32_16x16x32_bf16(qf[ks], kf, a, 0, 0, 0);
      }
      s[cg] = a;
    }
    __builtin_amdgcn_s_setprio(0);
    if (diag) mask_diag(s);
#pragma unroll
    for (int cg = 0; cg < 4; ++cg)
#pragma unroll
      for (int r = 0; r < 4; ++r) s[cg][r] = exp2f(s[cg][r]);
#pragma unroll
    for (int r = 0; r < 4; ++r)
      lsum[r] += (s[0][r] + s[1][r]) + (s[2][r] + s[3][r]);
#pragma unroll
    for (int cg = 0; cg < 4; ++cg)
#pragma unroll
      for (int r = 0; r < 4; ++r)
        Ps[wave][1][(lgrp * 4 + r) * 72 + cg * 16 + lmod] = f2bf_hw(s[cg][r]);
    __builtin_amdgcn_s_setprio(1);
#pragma unroll
    for (int ks = 0; ks < 2; ++ks) {
      bf16x8 pf = *reinterpret_cast<const bf16x8*>(
          &Ps[wave][1][lmod * 72 + ks * 32 + lgrp * 8]);
#pragma unroll
      for (int dhg = 0; dhg < 4; ++dhg) {
        bf16x8 vf = *reinterpret_cast<const bf16x8*>(
            &Vs[(dhg * 16 + lmod) * 72 + ks * 32 + lgrp * 8]);
        oacc[dhg] = __builtin_amdgcn_mfma_f32_16x16x32_bf16(pf, vf, oacc[dhg], 0, 0, 0);
      }
    }
    __builtin_amdgcn_s_setprio(0);
  };

  // dual step: both q-tiles share every K/V fragment (j <= p; diag_lo = j==p)
  auto step_dual = [&](bool diag_lo) {
    f32x4 sl[4], sh[4];
    __builtin_amdgcn_s_setprio(1);
#pragma unroll
    for (int cg = 0; cg < 4; ++cg) {
      f32x4 al = {}, ah = {};
#pragma unroll
      for (int ks = 0; ks < 2; ++ks) {
        bf16x8 kf = *reinterpret_cast<const bf16x8*>(
            &Ks[(cg * 16 + lmod) * 72 + ks * 32 + lgrp * 8]);
        al = __builtin_amdgcn_mfma_f32_16x16x32_bf16(qfl[ks], kf, al, 0, 0, 0);
        ah = __builtin_amdgcn_mfma_f32_16x16x32_bf16(qfh[ks], kf, ah, 0, 0, 0);
      }
      sl[cg] = al; sh[cg] = ah;
    }
    __builtin_amdgcn_s_setprio(0);
    if (diag_lo) mask_diag(sl);          // hi tile never diagonal here (p < jmax)
#pragma unroll
    for (int cg = 0; cg < 4; ++cg)
#pragma unroll
      for (int r = 0; r < 4; ++r) {
        sl[cg][r] = exp2f(sl[cg][r]);
        sh[cg][r] = exp2f(sh[cg][r]);
      }
#pragma unroll
    for (int r = 0; r < 4; ++r) {
      ll[r] += (sl[0][r] + sl[1][r]) + (sl[2][r] + sl[3][r]);
      lh[r] += (sh[0][r] + sh[1][r]) + (sh[2][r] + sh[3][r]);
    }
#pragma unroll
    for (int cg = 0; cg < 4; ++cg)
#pragma unroll
      for (int r = 0; r < 4; ++r) {
        Ps[wave][0][(lgrp * 4 + r) * 72 + cg * 16 + lmod] = f2bf_hw(sl[cg][r]);
        Ps[wave][1][(lgrp * 4 + r) * 72 + cg * 16 + lmod] = f2bf_hw(sh[cg][r]);
      }
    __builtin_amdgcn_s_setprio(1);
#pragma unroll
    for (int ks = 0; ks < 2; ++ks) {
      bf16x8 pfl = *reinterpret_cast<const bf16x8*>(
          &Ps[wave][0][lmod * 72 + ks * 32 + lgrp * 8]);
      bf16x8 pfh = *reinterpret_cast<const bf16x8*>(
          &Ps[wave][1][lmod * 72 + ks * 32 + lgrp * 8]);
#pragma unroll
      for (int dhg = 0; dhg < 4; ++dhg) {
        bf16x8 vf = *reinterpret_cast<const bf16x8*>(
            &Vs[(dhg * 16 + lmod) * 72 + ks * 32 + lgrp * 8]);
        ol[dhg] = __builtin_amdgcn_mfma_f32_16x16x32_bf16(pfl, vf, ol[dhg], 0, 0, 0);
        oh[dhg] = __builtin_amdgcn_mfma_f32_16x16x32_bf16(pfh, vf, oh[dhg], 0, 0, 0);
      }
    }
    __builtin_amdgcn_s_setprio(0);
  };

  load_tile(0);
  for (int j = 0; j <= jmax; ++j) {
    __syncthreads();
    write_tile();
    __syncthreads();
    if (j < jmax) load_tile(j + 1);
    if (j <= p) step_dual(j == p);       // block-uniform branch
    else step(qfh, oh, lh, j == jmax);
  }

#pragma unroll
  for (int m = 1; m <= 8; m <<= 1)
#pragma unroll
    for (int r = 0; r < 4; ++r) {
      ll[r] += __shfl_xor(ll[r], m);
      lh[r] += __shfl_xor(lh[r], m);
    }

#pragma unroll
  for (int dhg = 0; dhg < 4; ++dhg) {
    const int col = h * 64 + dhg * 16 + lmod;
#pragma unroll
    for (int r = 0; r < 4; ++r) {
      Og[(xrow0 + qlo + lgrp * 4 + r) * 1024 + col] = f2bf_hw(ol[dhg][r] / ll[r]);
      Og[(xrow0 + qhi + lgrp * 4 + r) * 1024 + col] = f2bf_hw(oh[dhg][r] / lh[r]);
    }
  }
}

// ---------------- launch ----------------

extern "C" void kernel_launch(void* const* d_in, const int* in_sizes, int n_in,
                              void* d_out, int out_size, void* d_ws, size_t ws_size,
                              hipStream_t stream) {
  const float* x  = (const float*)d_in[0];
  const float* Wq = (const float*)d_in[1];
  const float* bq = (const float*)d_in[2];
  const float* Wk = (const float*)d_in[3];
  const float* bk = (const float*)d_in[4];
  const float* Wv = (const float*)d_in[5];
  const float* bv = (const float*)d_in[6];
  const float* Wp = (const float*)d_in[7];
  const float* bp = (const float*)d_in[8];
  float* out = (float*)d_out;

  char* ws = (char*)d_ws;
  ushort_t* XB    = (ushort_t*)(ws);                  // 8MB; reused as ctx
  ushort_t* WQKVT = (ushort_t*)(ws + ( 8ull << 20));  // 6MB [3072][1024]
  ushort_t* WPT   = (ushort_t*)(ws + (14ull << 20));  // 2MB [1024][1024]
  ushort_t* QKVB  = (ushort_t*)(ws + (16ull << 20));  // 24MB [4096][3072] (V region unused)
  ushort_t* VT    = (ushort_t*)(ws + (40ull << 20));  // 8MB [64bh][64d][1024t]

  cvt_fused_kernel<<<8192, 256, 0, stream>>>(x, Wq, Wk, Wv, Wp, XB, WQKVT, WPT);
  gemm_qkv128_kernel<<<768, 256, 0, stream>>>(XB, WQKVT, bq, bk, bv, QKVB, VT);
  attn_kernel<<<512, 256, 0, stream>>>(QKVB, VT, XB);
  gemm_proj_kernel<<<512, 256, 0, stream>>>(XB, WPT, bp, out);
}